// Round 15
// baseline (54.219 us; speedup 1.0000x reference)
//
#include <hip/hip_runtime.h>
#include <hip/hip_fp16.h>

#define D 2
#define DH 5
#define NH 3
#define NW0 (DH*D)            // 10
#define NWS (NH*DH*DH)        // 75
#define NWTOT (NW0+NWS+D*DH)  // 95

// c = 2*log2(e): weights pre-scaled so exp2 needs no argument mul.
#define C_SCALE 2.8853900817779268f
#define K03C 0.10397207708399180f   // 0.3/c
#define K28C 0.97040605462392273f   // 2.8/c
#define LN2  0.69314718055994531f

// Packed f16 activation for one sample-pair: zp = c*z (both halves).
//   r = 1/(2^{zp}+1);  h = 0.3z+0.7-1.4r;  d' = 0.3/c + (2.8/c)(r-r^2)
__device__ __forceinline__ void act2h(__half2 zp, __half2& h, __half2& dp,
                                      __half2 one2, __half2 k03, __half2 k28,
                                      __half2 c07, __half2 n14) {
    __half2 e = h2exp2(zp);
    __half2 a = __hadd2(e, one2);
    __half2 r = h2rcp(a);
    __half2 u = __hfma2(__hneg2(r), r, r);            // r - r^2
    dp = __hfma2(k28, u, k03);
    h  = __hfma2(n14, r, __hfma2(k03, zp, c07));
}

// Pre-scale weights by c, convert to f16, splat into both halves of a uint32.
__global__ void prescale_kernel(const float* __restrict__ gW0,
                                const float* __restrict__ gWs,
                                const float* __restrict__ gWout,
                                unsigned int* __restrict__ wsu) {
    int i = threadIdx.x;
    float w;
    if (i < NW0)            w = gW0[i];
    else if (i < NW0+NWS)   w = gWs[i - NW0];
    else if (i < NWTOT)     w = gWout[i - NW0 - NWS];
    else return;
    __half hw = __float2half_rn(C_SCALE * w);
    unsigned short us = __half_as_ushort(hw);
    wsu[i] = (unsigned int)us | ((unsigned int)us << 16);
}

__global__ __launch_bounds__(256, 8) void nnflow_kernel(
    const float2* __restrict__ xj2,
    const unsigned int* __restrict__ wsu,
    float2* __restrict__ out2,
    int npairs)
{
    int t0 = blockIdx.x * blockDim.x + threadIdx.x;
    int nthreads = gridDim.x * blockDim.x;

    // ---- splatted f16 weight pairs, loaded ONCE per thread (SGPRs) ----
    unsigned int wu[NWTOT];
    #pragma unroll
    for (int i = 0; i < NWTOT; ++i) wu[i] = wsu[i];
    #define W0H(k,j)   __builtin_bit_cast(__half2, wu[(k)*D+(j)])
    #define WSH(i,k,j) __builtin_bit_cast(__half2, wu[NW0 + ((i)*DH+(k))*DH+(j)])
    #define WOH(r,j)   __builtin_bit_cast(__half2, wu[NW0+NWS+(r)*DH+(j)])

    const __half2 one2 = __float2half2_rn(1.0f);
    const __half2 k03  = __float2half2_rn(K03C);
    const __half2 k28  = __float2half2_rn(K28C);
    const __half2 c07  = __float2half2_rn(0.7f);
    const __half2 n14  = __float2half2_rn(-1.4f);

    // ---- grid-stride (2 iters/thread at 4096 blocks): prologue amortized,
    //      16 blocks/CU of scheduling slack (R14's exact-fit tail fixed) ----
    for (int t = t0; t < npairs; t += nthreads) {
        float2 f0 = xj2[(size_t)t * 3 + 0];
        float2 f1 = xj2[(size_t)t * 3 + 1];
        float2 f2 = xj2[(size_t)t * 3 + 2];

        __half2 x0 = __floats2half2_rn(f0.x, f1.y);   // (x0_a, x0_b)
        __half2 x1 = __floats2half2_rn(f0.y, f2.x);   // (x1_a, x1_b)
        float lj[2] = { f1.x, f2.y };

        // ---- layer 0 ----
        __half2 h[DH], J0[DH], J1[DH];
        #pragma unroll
        for (int k = 0; k < DH; ++k) {
            __half2 z = __hfma2(W0H(k,0), x0, __hmul2(W0H(k,1), x1));
            __half2 hk, dk;
            act2h(z, hk, dk, one2, k03, k28, c07, n14);
            h[k]  = hk;
            J0[k] = __hmul2(W0H(k,0), dk);
            J1[k] = __hmul2(W0H(k,1), dk);
        }

        // ---- hidden layers ----
        #pragma unroll
        for (int i = 0; i < NH; ++i) {
            __half2 hn[DH], Jn0[DH], Jn1[DH];
            #pragma unroll
            for (int k = 0; k < DH; ++k) {
                __half2 z  = __hmul2(WSH(i,k,0), h[0]);
                __half2 j0 = __hmul2(WSH(i,k,0), J0[0]);
                __half2 j1 = __hmul2(WSH(i,k,0), J1[0]);
                #pragma unroll
                for (int j = 1; j < DH; ++j) {
                    __half2 w = WSH(i,k,j);
                    z  = __hfma2(w, h[j],  z);
                    j0 = __hfma2(w, J0[j], j0);
                    j1 = __hfma2(w, J1[j], j1);
                }
                __half2 hk, dk;
                act2h(z, hk, dk, one2, k03, k28, c07, n14);
                hn[k]  = hk;
                Jn0[k] = __hmul2(dk, j0);
                Jn1[k] = __hmul2(dk, j1);
            }
            #pragma unroll
            for (int k = 0; k < DH; ++k) {
                h[k] = hn[k]; J0[k] = Jn0[k]; J1[k] = Jn1[k];
            }
        }

        // ---- output layer ----
        __half2 y[2], dpv[2], o0[2], o1[2];
        #pragma unroll
        for (int r = 0; r < 2; ++r) {
            __half2 z  = __hmul2(WOH(r,0), h[0]);
            __half2 j0 = __hmul2(WOH(r,0), J0[0]);
            __half2 j1 = __hmul2(WOH(r,0), J1[0]);
            #pragma unroll
            for (int j = 1; j < DH; ++j) {
                __half2 w = WOH(r,j);
                z  = __hfma2(w, h[j],  z);
                j0 = __hfma2(w, J0[j], j0);
                j1 = __hfma2(w, J1[j], j1);
            }
            __half2 yk, dk;
            act2h(z, yk, dk, one2, k03, k28, c07, n14);
            y[r] = yk; dpv[r] = dk;
            o0[r] = j0; o1[r] = j1;
        }

        // ---- det + log in f32 (both samples) ----
        float ry0[2], ry1[2], rld[2];
        #pragma unroll
        for (int hx = 0; hx < 2; ++hx) {
            float a00 = (hx ? __high2float(o0[0]) : __low2float(o0[0]));
            float a01 = (hx ? __high2float(o1[0]) : __low2float(o1[0]));
            float a10 = (hx ? __high2float(o0[1]) : __low2float(o0[1]));
            float a11 = (hx ? __high2float(o1[1]) : __low2float(o1[1]));
            float d0  = (hx ? __high2float(dpv[0]) : __low2float(dpv[0]));
            float d1  = (hx ? __high2float(dpv[1]) : __low2float(dpv[1]));
            float cross = fmaf(-a01, a10, a00 * a11);
            float det   = (d0 * d1) * cross;
            float lg    = __builtin_amdgcn_logf(fabsf(det));
            rld[hx] = fmaf(LN2, lg, lj[hx]);
            ry0[hx] = (hx ? __high2float(y[0]) : __low2float(y[0]));
            ry1[hx] = (hx ? __high2float(y[1]) : __low2float(y[1]));
        }

        // ---- 6 floats -> 3 float2 stores ----
        out2[(size_t)t * 3 + 0] = make_float2(ry0[0], ry1[0]);
        out2[(size_t)t * 3 + 1] = make_float2(rld[0], ry0[1]);
        out2[(size_t)t * 3 + 2] = make_float2(ry1[1], rld[1]);
    }
}

extern "C" void kernel_launch(void* const* d_in, const int* in_sizes, int n_in,
                              void* d_out, int out_size, void* d_ws, size_t ws_size,
                              hipStream_t stream) {
    const float* xj   = (const float*)d_in[0];
    const float* W0   = (const float*)d_in[1];
    const float* Ws   = (const float*)d_in[2];
    const float* Wout = (const float*)d_in[3];
    float* out = (float*)d_out;
    unsigned int* wsu = (unsigned int*)d_ws;

    prescale_kernel<<<1, 128, 0, stream>>>(W0, Ws, Wout, wsu);

    int n = in_sizes[0] / (D + 1);   // 4194304
    int npairs = n / 2;              // 2,097,152 pairs

    // 4096 blocks x 256 threads = 1,048,576 threads, 2 pairs each:
    // prologue amortized 2x, 16 blocks/CU of scheduler slack.
    dim3 block(256);
    dim3 grid(4096);
    nnflow_kernel<<<grid, block, 0, stream>>>(
        (const float2*)xj, wsu, (float2*)out, npairs);
}

// Round 16
// 50.118 us; speedup vs baseline: 1.0818x; 1.0818x over previous
//
#include <hip/hip_runtime.h>
#include <hip/hip_fp16.h>

#define D 2
#define DH 5
#define NH 3
#define NW0 (DH*D)            // 10
#define NWS (NH*DH*DH)        // 75
#define NWTOT (NW0+NWS+D*DH)  // 95

// c = 2*log2(e): weights pre-scaled so exp2 needs no argument mul.
#define C_SCALE 2.8853900817779268f
#define K03C 0.10397207708399180f   // 0.3/c
#define K28C 0.97040605462392273f   // 2.8/c
#define LN2  0.69314718055994531f

// Packed f16 activation for one sample-pair: zp = c*z (both halves).
//   r = 1/(2^{zp}+1);  h = 0.3z+0.7-1.4r;  d' = 0.3/c + (2.8/c)(r-r^2)
__device__ __forceinline__ void act2h(__half2 zp, __half2& h, __half2& dp,
                                      __half2 one2, __half2 k03, __half2 k28,
                                      __half2 c07, __half2 n14) {
    __half2 e = h2exp2(zp);
    __half2 a = __hadd2(e, one2);
    __half2 r = h2rcp(a);
    __half2 u = __hfma2(__hneg2(r), r, r);            // r - r^2
    dp = __hfma2(k28, u, k03);
    h  = __hfma2(n14, r, __hfma2(k03, zp, c07));
}

// Pre-scale weights by c, convert to f16, splat into both halves of a uint32.
__global__ void prescale_kernel(const float* __restrict__ gW0,
                                const float* __restrict__ gWs,
                                const float* __restrict__ gWout,
                                unsigned int* __restrict__ wsu) {
    int i = threadIdx.x;
    float w;
    if (i < NW0)            w = gW0[i];
    else if (i < NW0+NWS)   w = gWs[i - NW0];
    else if (i < NWTOT)     w = gWout[i - NW0 - NWS];
    else return;
    __half hw = __float2half_rn(C_SCALE * w);
    unsigned short us = __half_as_ushort(hw);
    wsu[i] = (unsigned int)us | ((unsigned int)us << 16);
}

__global__ __launch_bounds__(256) void nnflow_kernel(
    const float2* __restrict__ xj2,
    const unsigned int* __restrict__ wsu,
    float2* __restrict__ out2,
    int npairs)
{
    int t = blockIdx.x * blockDim.x + threadIdx.x;
    if (t >= npairs) return;

    // ---- splatted f16 weight pairs (uniform -> SGPRs) ----
    unsigned int wu[NWTOT];
    #pragma unroll
    for (int i = 0; i < NWTOT; ++i) wu[i] = wsu[i];
    #define W0H(k,j)   __builtin_bit_cast(__half2, wu[(k)*D+(j)])
    #define WSH(i,k,j) __builtin_bit_cast(__half2, wu[NW0 + ((i)*DH+(k))*DH+(j)])
    #define WOH(r,j)   __builtin_bit_cast(__half2, wu[NW0+NWS+(r)*DH+(j)])

    const __half2 one2 = __float2half2_rn(1.0f);
    const __half2 k03  = __float2half2_rn(K03C);
    const __half2 k28  = __float2half2_rn(K28C);
    const __half2 c07  = __float2half2_rn(0.7f);
    const __half2 n14  = __float2half2_rn(-1.4f);

    // ---- 2 samples = 6 floats = 3 float2 (8B-aligned, coalesced) ----
    float2 f0 = xj2[(size_t)t * 3 + 0];
    float2 f1 = xj2[(size_t)t * 3 + 1];
    float2 f2 = xj2[(size_t)t * 3 + 2];

    __half2 x0 = __floats2half2_rn(f0.x, f1.y);   // (x0_a, x0_b)
    __half2 x1 = __floats2half2_rn(f0.y, f2.x);   // (x1_a, x1_b)
    float lj[2] = { f1.x, f2.y };

    // ---- layer 0 ----
    __half2 h[DH], J0[DH], J1[DH];
    #pragma unroll
    for (int k = 0; k < DH; ++k) {
        __half2 z = __hfma2(W0H(k,0), x0, __hmul2(W0H(k,1), x1));
        __half2 hk, dk;
        act2h(z, hk, dk, one2, k03, k28, c07, n14);
        h[k]  = hk;
        J0[k] = __hmul2(W0H(k,0), dk);
        J1[k] = __hmul2(W0H(k,1), dk);
    }

    // ---- hidden layers ----
    #pragma unroll
    for (int i = 0; i < NH; ++i) {
        __half2 hn[DH], Jn0[DH], Jn1[DH];
        #pragma unroll
        for (int k = 0; k < DH; ++k) {
            __half2 z  = __hmul2(WSH(i,k,0), h[0]);
            __half2 j0 = __hmul2(WSH(i,k,0), J0[0]);
            __half2 j1 = __hmul2(WSH(i,k,0), J1[0]);
            #pragma unroll
            for (int j = 1; j < DH; ++j) {
                __half2 w = WSH(i,k,j);
                z  = __hfma2(w, h[j],  z);
                j0 = __hfma2(w, J0[j], j0);
                j1 = __hfma2(w, J1[j], j1);
            }
            __half2 hk, dk;
            act2h(z, hk, dk, one2, k03, k28, c07, n14);
            hn[k]  = hk;
            Jn0[k] = __hmul2(dk, j0);
            Jn1[k] = __hmul2(dk, j1);
        }
        #pragma unroll
        for (int k = 0; k < DH; ++k) {
            h[k] = hn[k]; J0[k] = Jn0[k]; J1[k] = Jn1[k];
        }
    }

    // ---- output layer ----
    __half2 y[2], dpv[2], o0[2], o1[2];
    #pragma unroll
    for (int r = 0; r < 2; ++r) {
        __half2 z  = __hmul2(WOH(r,0), h[0]);
        __half2 j0 = __hmul2(WOH(r,0), J0[0]);
        __half2 j1 = __hmul2(WOH(r,0), J1[0]);
        #pragma unroll
        for (int j = 1; j < DH; ++j) {
            __half2 w = WOH(r,j);
            z  = __hfma2(w, h[j],  z);
            j0 = __hfma2(w, J0[j], j0);
            j1 = __hfma2(w, J1[j], j1);
        }
        __half2 yk, dk;
        act2h(z, yk, dk, one2, k03, k28, c07, n14);
        y[r] = yk; dpv[r] = dk;
        o0[r] = j0; o1[r] = j1;
    }

    // ---- det + log in f32 (both samples) ----
    float ry0[2], ry1[2], rld[2];
    #pragma unroll
    for (int hx = 0; hx < 2; ++hx) {
        float a00 = (hx ? __high2float(o0[0]) : __low2float(o0[0]));
        float a01 = (hx ? __high2float(o1[0]) : __low2float(o1[0]));
        float a10 = (hx ? __high2float(o0[1]) : __low2float(o0[1]));
        float a11 = (hx ? __high2float(o1[1]) : __low2float(o1[1]));
        float d0  = (hx ? __high2float(dpv[0]) : __low2float(dpv[0]));
        float d1  = (hx ? __high2float(dpv[1]) : __low2float(dpv[1]));
        float cross = fmaf(-a01, a10, a00 * a11);
        float det   = (d0 * d1) * cross;
        float lg    = __builtin_amdgcn_logf(fabsf(det));
        rld[hx] = fmaf(LN2, lg, lj[hx]);
        ry0[hx] = (hx ? __high2float(y[0]) : __low2float(y[0]));
        ry1[hx] = (hx ? __high2float(y[1]) : __low2float(y[1]));
    }

    // ---- 6 floats -> 3 float2 stores ----
    out2[(size_t)t * 3 + 0] = make_float2(ry0[0], ry1[0]);
    out2[(size_t)t * 3 + 1] = make_float2(rld[0], ry0[1]);
    out2[(size_t)t * 3 + 2] = make_float2(ry1[1], rld[1]);
}

extern "C" void kernel_launch(void* const* d_in, const int* in_sizes, int n_in,
                              void* d_out, int out_size, void* d_ws, size_t ws_size,
                              hipStream_t stream) {
    const float* xj   = (const float*)d_in[0];
    const float* W0   = (const float*)d_in[1];
    const float* Ws   = (const float*)d_in[2];
    const float* Wout = (const float*)d_in[3];
    float* out = (float*)d_out;
    unsigned int* wsu = (unsigned int*)d_ws;

    prescale_kernel<<<1, 128, 0, stream>>>(W0, Ws, Wout, wsu);

    int n = in_sizes[0] / (D + 1);   // 4194304
    int npairs = n / 2;              // 2,097,152 threads, 2 samples each

    dim3 block(256);
    dim3 grid((npairs + block.x - 1) / block.x);
    nnflow_kernel<<<grid, block, 0, stream>>>(
        (const float2*)xj, wsu, (float2*)out, npairs);
}